// Round 7
// baseline (598.930 us; speedup 1.0000x reference)
//
#include <hip/hip_runtime.h>
#include <stdint.h>

typedef float    f32x4 __attribute__((ext_vector_type(4)));
typedef uint32_t u32x4 __attribute__((ext_vector_type(4)));

#define NN 5000
#define NE 80000
#define NF 128
#define NT 16
#define TN 10
#define NFW 3
#define NSK 10
#define PW (1.0f/5000.0f)
#define RB 128          // kM threads per row-block
#define GRX 40
#define NBT 16          // blocks per template (coop kernels)
#define TPB 320         // threads per coop block (5 waves)
#define RPB 313         // rows per coop block

// ---------- workspace layout (bytes) ----------
#define OFF_DEG  0u
#define OFF_RP   20224u
#define OFF_CUR  40448u
#define OFF_COL  60672u      // 320000 -> 380672
#define OFF_SC   380672u     // 384 f32: [t*16+k]=sabs; [64+(t*16+k)*4+d]=dots(bM,bC,bA,aA);
                             // [256+k*4+d]=fin; int[320+t*16+k]=barrier ctr (t=0..3)
#define OFF_CS   382208u     // csg: [3][10][16][16] f32 = 30720 B -> 412928
#define OFF_M    416000u     // f32 [16][5000][12] -> 4,256,000
#define OFF_T    4256000u    // f32 -> 8,096,000
#define OFF_ATM  8096000u    // ATC bf16 hi-part u32x4 -> 9,376,000
#define OFF_ATT  9376000u    // ATC bf16 tail u32 -> 9,696,000
#define OFF_DTM  9696000u    // dT bf16 -> 10,976,000
#define OFF_DTT  10976000u   // -> 11,296,000
#define OFF_Y2M  11296000u   // Y2 = dT@C2 bf16 -> 12,576,000
#define OFF_Y2T  12576000u   // -> 12,896,000
#define SC_FLOATS 384
#define CS_FLOATS 7680

// ---------- helpers ----------
__device__ __forceinline__ uint32_t bfb(float x) {
  uint32_t u = __float_as_uint(x);
  return (u + 0x7fffu + ((u >> 16) & 1u)) >> 16;
}
__device__ __forceinline__ uint32_t pk(float a, float b) { return bfb(a) | (bfb(b) << 16); }
__device__ __forceinline__ float ubl(uint32_t u) { return __uint_as_float(u << 16); }
__device__ __forceinline__ float ubh(uint32_t u) { return __uint_as_float(u & 0xffff0000u); }
__device__ __forceinline__ float sigm(float z) { return 1.f / (1.f + __expf(-z)); }

__device__ __forceinline__ void ld12(const float* p, float* v) {
  f32x4 a = *(const f32x4*)p, b = *(const f32x4*)(p + 4), c = *(const f32x4*)(p + 8);
  v[0]=a[0]; v[1]=a[1]; v[2]=a[2]; v[3]=a[3]; v[4]=b[0]; v[5]=b[1]; v[6]=b[2]; v[7]=b[3];
  v[8]=c[0]; v[9]=c[1];
}
__device__ __forceinline__ void st12(float* p, const float* v) {
  *(f32x4*)p       = (f32x4){v[0], v[1], v[2], v[3]};
  *(f32x4*)(p + 4) = (f32x4){v[4], v[5], v[6], v[7]};
  *(f32x4*)(p + 8) = (f32x4){v[8], v[9], 0.f, 0.f};
}
__device__ __forceinline__ void ldbf(const u32x4* __restrict__ M4, const uint32_t* __restrict__ M1,
                                     size_t i, float* v) {
  u32x4 A = M4[i]; uint32_t B = M1[i];
  v[0]=ubl(A[0]); v[1]=ubh(A[0]); v[2]=ubl(A[1]); v[3]=ubh(A[1]);
  v[4]=ubl(A[2]); v[5]=ubh(A[2]); v[6]=ubl(A[3]); v[7]=ubh(A[3]);
  v[8]=ubl(B);    v[9]=ubh(B);
}
__device__ __forceinline__ void stbf(u32x4* __restrict__ M4, uint32_t* __restrict__ M1,
                                     size_t i, const float* v) {
  M4[i] = (u32x4){pk(v[0], v[1]), pk(v[2], v[3]), pk(v[4], v[5]), pk(v[6], v[7])};
  M1[i] = pk(v[8], v[9]);
}
__device__ __forceinline__ void gath(const u32x4* __restrict__ YM, const uint32_t* __restrict__ YT,
                                     const int* __restrict__ col, int e0, int e1, float* acc) {
  for (int e = e0; e < e1; ++e) {
    int c = col[e];
    u32x4 A = YM[c]; uint32_t B = YT[c];
    acc[0] += ubl(A[0]); acc[1] += ubh(A[0]); acc[2] += ubl(A[1]); acc[3] += ubh(A[1]);
    acc[4] += ubl(A[2]); acc[5] += ubh(A[2]); acc[6] += ubl(A[3]); acc[7] += ubh(A[3]);
    acc[8] += ubl(B);    acc[9] += ubh(B);
  }
}
__device__ __forceinline__ float ga_readf(float* p) {
  return __hip_atomic_fetch_add(p, 0.0f, __ATOMIC_RELAXED, __HIP_MEMORY_SCOPE_AGENT);
}
// per-template spin barrier (R3-proven): relaxed IF RMW, no cache maintenance
__device__ __forceinline__ void tbar(int* ctr, int target) {
  asm volatile("s_waitcnt vmcnt(0)" ::: "memory");
  __syncthreads();
  if (threadIdx.x == 0) {
    __hip_atomic_fetch_add(ctr, 1, __ATOMIC_RELAXED, __HIP_MEMORY_SCOPE_AGENT);
    while (__hip_atomic_fetch_add(ctr, 0, __ATOMIC_RELAXED, __HIP_MEMORY_SCOPE_AGENT) < target)
      __builtin_amdgcn_s_sleep(8);
  }
  __syncthreads();
}
// block reduce (5 waves)
__device__ __forceinline__ float bred(float v, float* red) {
  #pragma unroll
  for (int o = 32; o; o >>= 1) v += __shfl_xor(v, o, 64);
  __syncthreads();
  if ((threadIdx.x & 63) == 0) red[threadIdx.x >> 6] = v;
  __syncthreads();
  return red[0] + red[1] + red[2] + red[3] + red[4];
}

// ---------- setup kernels ----------
__global__ void k_init(char* __restrict__ ws) {
  int g = blockIdx.x * 256 + threadIdx.x;
  if (g < NN) ((int*)(ws + OFF_DEG))[g] = 0;
  int z = g - NN;
  if (z >= 0 && z < SC_FLOATS) ((float*)(ws + OFF_SC))[z] = 0.f;
  int c = g - (NN + SC_FLOATS);
  if (c >= 0 && c < CS_FLOATS) ((float*)(ws + OFF_CS))[c] = 0.f;
}
__global__ void k_deg(const int* __restrict__ ei, int* __restrict__ deg) {
  int e = blockIdx.x * 256 + threadIdx.x;
  if (e < NE) atomicAdd(&deg[ei[e]], 1);
}
__global__ void k_scan(const int* __restrict__ deg, int* __restrict__ rowptr, int* __restrict__ cur) {
  __shared__ int scr[1024];
  int tid = threadIdx.x;
  int loc[5], s = 0;
  #pragma unroll
  for (int r = 0; r < 5; ++r) {
    int idx = tid * 5 + r;
    int d = (idx < NN) ? deg[idx] : 0;
    loc[r] = s; s += d;
  }
  scr[tid] = s; __syncthreads();
  for (int off = 1; off < 1024; off <<= 1) {
    int v = scr[tid];
    int u = (tid >= off) ? scr[tid - off] : 0;
    __syncthreads();
    scr[tid] = v + u;
    __syncthreads();
  }
  int base = (tid > 0) ? scr[tid - 1] : 0;
  #pragma unroll
  for (int r = 0; r < 5; ++r) {
    int idx = tid * 5 + r;
    if (idx < NN) { int v = base + loc[r]; rowptr[idx] = v; cur[idx] = v; }
  }
  if (tid == 1023) rowptr[NN] = scr[1023];
}
__global__ void k_fill(const int* __restrict__ ei, int* __restrict__ cur, int* __restrict__ col) {
  int e = blockIdx.x * 256 + threadIdx.x;
  if (e < NE) {
    int s = ei[e];
    int pos = atomicAdd(&cur[s], 1);
    col[pos] = ei[NE + e];
  }
}
// ---------- M build ----------
__global__ void kM(const float* __restrict__ x, const float* __restrict__ F2,
                   float* __restrict__ Mb) {
  __shared__ float ffs[TN];
  const int k = blockIdx.y, tid = threadIdx.x;
  const int i = blockIdx.x * RB + tid;
  const float* Fk = F2 + (size_t)k * TN * NF;
  if (tid < TN) {
    float s = 0.f;
    for (int d = 0; d < NF; ++d) { float f = Fk[tid * NF + d]; s += f * f; }
    ffs[tid] = s;
  }
  __syncthreads();
  if (i >= NN) return;
  const f32x4* xr = (const f32x4*)(x + (size_t)i * NF);
  float acc[TN];
  #pragma unroll
  for (int j = 0; j < TN; ++j) acc[j] = 0.f;
  float xsq = 0.f;
  for (int dc = 0; dc < NF / 4; ++dc) {
    f32x4 xv = xr[dc];
    xsq += xv[0]*xv[0] + xv[1]*xv[1] + xv[2]*xv[2] + xv[3]*xv[3];
    #pragma unroll
    for (int j = 0; j < TN; ++j) {
      const float* Fj = Fk + j * NF + dc * 4;  // uniform -> scalar loads
      acc[j] += xv[0]*Fj[0] + xv[1]*Fj[1] + xv[2]*Fj[2] + xv[3]*Fj[3];
    }
  }
  float v[TN];
  #pragma unroll
  for (int j = 0; j < TN; ++j) v[j] = xsq + ffs[j] - 2.f * acc[j];
  st12(Mb + ((size_t)k * NN + i) * 12, v);
}

// ---------- kFW: one full Frank-Wolfe iteration (cooperative, 256 blocks) ----------
// head: [t>0] gather Y2 -> adt, dots bA/aA, barrier, gamma, T/ATC update
// mid:  G in regs, sabs barrier, E = exp, 10x Sinkhorn (1 barrier each)
// tail: dT = Tn - T (bf16), Y2 = dT@C2 (bf16), dots bM/bC
__global__ __launch_bounds__(TPB, 2) void kFW(
    const int* __restrict__ rowptr, const int* __restrict__ col,
    const float* __restrict__ Mb, float* __restrict__ Tb,
    u32x4* __restrict__ AtM, uint32_t* __restrict__ AtT,
    u32x4* __restrict__ DtM, uint32_t* __restrict__ DtT,
    u32x4* __restrict__ Y2M, uint32_t* __restrict__ Y2T,
    const float* __restrict__ q0, const float* __restrict__ C2g,
    const float* __restrict__ a0p, float* __restrict__ sc,
    float* __restrict__ csg, int t) {
  __shared__ float red[80];
  __shared__ float csb[16];
  __shared__ float qvs[16], c2qs[16], qC2s[16];
  const int bid = blockIdx.x;
  const int k = bid >> 4, b = bid & (NBT - 1);
  const int tid = threadIdx.x;
  const float* C2k = C2g + k * 100;
  if (tid < TN) {
    float mx = -1e30f, e[TN], s = 0.f;
    #pragma unroll
    for (int j = 0; j < TN; ++j) mx = fmaxf(mx, q0[k * TN + j]);
    #pragma unroll
    for (int j = 0; j < TN; ++j) { e[j] = __expf(q0[k * TN + j] - mx); s += e[j]; }
    float inv = 1.f / s;
    qvs[tid] = e[tid] * inv;
    float c2 = 0.f, qc = 0.f;
    #pragma unroll
    for (int l = 0; l < TN; ++l) {
      float c = C2k[tid * TN + l];
      c2 += c * c * e[l] * inv;
      qc += e[l] * inv * C2k[l * TN + tid];
    }
    c2qs[tid] = c2; qC2s[tid] = qc;
  }
  __syncthreads();
  const float alpha = sigm(a0p[0]), oma = 1.f - alpha;
  int* ctr = (int*)sc + 320 + t * 16 + k;
  int barno = 0;

  const int r = b * RPB + tid;
  const bool own = (tid < RPB) && (r < NN);
  int e0 = 0, e1 = 0;
  if (own) { e0 = rowptr[r]; e1 = rowptr[r + 1]; }
  const float cc = (float)(e1 - e0) * PW;
  const size_t bi = (size_t)k * NN + (own ? r : 0);

  float Tr[TN], Ar[TN];
  if (t == 0) {
    if (own) {
      #pragma unroll
      for (int j = 0; j < TN; ++j) { Tr[j] = PW * qvs[j]; Ar[j] = (float)(e1 - e0) * PW * qC2s[j]; }
    }
  } else {
    float adt[TN] = {0,0,0,0,0,0,0,0,0,0};
    float av[TN], dv[TN];
    float bA = 0.f, aA = 0.f;
    if (own) {
      gath(Y2M + (size_t)k * NN, Y2T + (size_t)k * NN, col, e0, e1, adt);
      ldbf(AtM, AtT, bi, av); ldbf(DtM, DtT, bi, dv);
      #pragma unroll
      for (int j = 0; j < TN; ++j) { bA += av[j] * dv[j]; aA += adt[j] * dv[j]; }
    }
    bA = bred(bA, red); aA = bred(aA, red);
    float* dk = sc + 64 + (size_t)((t - 1) * NT + k) * 4;
    if (tid == 0) { atomicAdd(dk + 2, bA); atomicAdd(dk + 3, aA); }
    tbar(ctr, ++barno * NBT);
    if (tid < 4) csb[tid] = ga_readf(dk + tid);
    __syncthreads();
    float a_ = -2.f * alpha * csb[3];
    float b_ = oma * csb[0] + alpha * (csb[1] - 4.f * csb[2]);
    float gamma = (a_ > 0.f) ? fminf(fmaxf(-b_ / (2.f * a_ + 1e-16f), 0.f), 1.f)
                             : ((a_ + b_ < 0.f) ? 1.f : 0.f);
    if (own) {
      float tv[TN]; ld12(Tb + bi * 12, tv);
      #pragma unroll
      for (int j = 0; j < TN; ++j) { Tr[j] = tv[j] + gamma * dv[j]; Ar[j] = av[j] + gamma * adt[j]; }
    }
  }
  float Mr[TN], Er[TN];
  float sabs = 0.f;
  if (own) {
    st12(Tb + bi * 12, Tr);
    stbf(AtM, AtT, bi, Ar);
    ld12(Mb + bi * 12, Mr);
    #pragma unroll
    for (int j = 0; j < TN; ++j) {
      float G = oma * Mr[j] + 2.f * alpha * (cc + c2qs[j] - 2.f * Ar[j]);
      Er[j] = G; sabs += fabsf(G);
    }
  }
  sabs = bred(sabs, red);
  if (tid == 0) atomicAdd(sc + t * NT + k, sabs);
  tbar(ctr, ++barno * NBT);
  if (tid == 0) csb[0] = ga_readf(sc + t * NT + k);
  __syncthreads();
  const float invreg = 1.f / (0.05f * csb[0] * (1.f / (float)(NN * TN)) + 1e-9f);
  if (own) {
    float mn = Er[0];
    #pragma unroll
    for (int j = 1; j < TN; ++j) mn = fminf(mn, Er[j]);
    #pragma unroll
    for (int j = 0; j < TN; ++j) Er[j] = __expf(-(Er[j] - mn) * invreg);
  } else {
    #pragma unroll
    for (int j = 0; j < TN; ++j) Er[j] = 0.f;
  }

  // ---- Sinkhorn: 10 iterations, one IF barrier each ----
  float wlr[TN], wpr[TN];
  #pragma unroll
  for (int j = 0; j < TN; ++j) { wlr[j] = 1.f; wpr[j] = 1.f; }
  for (int it = 0; it < NSK; ++it) {
    float dot = 0.f;
    #pragma unroll
    for (int j = 0; j < TN; ++j) dot += Er[j] * wlr[j];
    float u = PW * __builtin_amdgcn_rcpf(fmaxf(dot, 1e-35f));
    float csl[TN];
    #pragma unroll
    for (int j = 0; j < TN; ++j) csl[j] = Er[j] * u;
    #pragma unroll
    for (int j = 0; j < TN; ++j) {
      float vv = csl[j];
      #pragma unroll
      for (int o = 32; o; o >>= 1) vv += __shfl_xor(vv, o, 64);
      if ((tid & 63) == j) red[(tid >> 6) * 16 + j] = vv;
    }
    __syncthreads();
    float* cell = csg + (size_t)((t * NSK + it) * NT + k) * 16;
    if (tid < TN) {
      float s = red[tid] + red[16 + tid] + red[32 + tid] + red[48 + tid] + red[64 + tid];
      atomicAdd(cell + tid, s);
    }
    tbar(ctr, ++barno * NBT);
    if (tid < TN) csb[tid] = ga_readf(cell + tid);
    __syncthreads();
    #pragma unroll
    for (int j = 0; j < TN; ++j) {
      wpr[j] = wlr[j];
      wlr[j] = qvs[j] * __builtin_amdgcn_rcpf(fmaxf(csb[j], 1e-35f));
    }
  }

  // ---- tail: dT, Y2, bM/bC ----
  float bM = 0.f, bC = 0.f;
  if (own) {
    float dot = 0.f;
    #pragma unroll
    for (int j = 0; j < TN; ++j) dot += Er[j] * wpr[j];
    float u = PW * __builtin_amdgcn_rcpf(fmaxf(dot, 1e-35f));
    float dT[TN];
    #pragma unroll
    for (int j = 0; j < TN; ++j) {
      float tn = u * Er[j] * wlr[j];
      dT[j] = tn - Tr[j];
      bM += Mr[j] * dT[j];
      bC += (cc + c2qs[j]) * dT[j];
    }
    stbf(DtM, DtT, bi, dT);
    float y[TN];
    #pragma unroll
    for (int j = 0; j < TN; ++j) {
      float s = 0.f;
      #pragma unroll
      for (int l = 0; l < TN; ++l) s += dT[l] * C2k[l * TN + j];
      y[j] = s;
    }
    stbf(Y2M, Y2T, bi, y);
  }
  bM = bred(bM, red); bC = bred(bC, red);
  float* dk2 = sc + 64 + (size_t)(t * NT + k) * 4;
  if (tid == 0) { atomicAdd(dk2 + 0, bM); atomicAdd(dk2 + 1, bC); }
}

// ---------- kFin: final gather-dots, gamma, distance (cooperative) ----------
__global__ __launch_bounds__(TPB, 2) void kFin(
    const int* __restrict__ rowptr, const int* __restrict__ col,
    const float* __restrict__ Mb, const float* __restrict__ Tb,
    const u32x4* __restrict__ AtM, const uint32_t* __restrict__ AtT,
    const u32x4* __restrict__ DtM, const uint32_t* __restrict__ DtT,
    const u32x4* __restrict__ Y2M, const uint32_t* __restrict__ Y2T,
    const float* __restrict__ q0, const float* __restrict__ C2g,
    const float* __restrict__ a0p, float* __restrict__ sc,
    float* __restrict__ out) {
  __shared__ float red[80];
  __shared__ float csb[16];
  __shared__ float c2qs[16];
  const int bid = blockIdx.x;
  const int k = bid >> 4, b = bid & (NBT - 1);
  const int tid = threadIdx.x;
  const float* C2k = C2g + k * 100;
  if (tid < TN) {
    float mx = -1e30f, e[TN], s = 0.f;
    #pragma unroll
    for (int j = 0; j < TN; ++j) mx = fmaxf(mx, q0[k * TN + j]);
    #pragma unroll
    for (int j = 0; j < TN; ++j) { e[j] = __expf(q0[k * TN + j] - mx); s += e[j]; }
    float inv = 1.f / s, c2 = 0.f;
    #pragma unroll
    for (int l = 0; l < TN; ++l) { float c = C2k[tid * TN + l]; c2 += c * c * e[l] * inv; }
    c2qs[tid] = c2;
  }
  __syncthreads();
  const float alpha = sigm(a0p[0]), oma = 1.f - alpha;
  int* ctr = (int*)sc + 320 + 3 * 16 + k;
  const int r = b * RPB + tid;
  const bool own = (tid < RPB) && (r < NN);
  int e0 = 0, e1 = 0;
  if (own) { e0 = rowptr[r]; e1 = rowptr[r + 1]; }
  const float cc = (float)(e1 - e0) * PW;
  const size_t bi = (size_t)k * NN + (own ? r : 0);

  float adt[TN] = {0,0,0,0,0,0,0,0,0,0};
  float av[TN], dv[TN];
  float bA = 0.f, aA = 0.f;
  if (own) {
    gath(Y2M + (size_t)k * NN, Y2T + (size_t)k * NN, col, e0, e1, adt);
    ldbf(AtM, AtT, bi, av); ldbf(DtM, DtT, bi, dv);
    #pragma unroll
    for (int j = 0; j < TN; ++j) { bA += av[j] * dv[j]; aA += adt[j] * dv[j]; }
  }
  bA = bred(bA, red); aA = bred(aA, red);
  float* dk = sc + 64 + (size_t)((NFW - 1) * NT + k) * 4;
  if (tid == 0) { atomicAdd(dk + 2, bA); atomicAdd(dk + 3, aA); }
  tbar(ctr, 1 * NBT);
  if (tid < 4) csb[tid] = ga_readf(dk + tid);
  __syncthreads();
  float a_ = -2.f * alpha * csb[3];
  float b_ = oma * csb[0] + alpha * (csb[1] - 4.f * csb[2]);
  float gamma = (a_ > 0.f) ? fminf(fmaxf(-b_ / (2.f * a_ + 1e-16f), 0.f), 1.f)
                           : ((a_ + b_ < 0.f) ? 1.f : 0.f);
  float d1 = 0.f, d2 = 0.f, d3 = 0.f;
  if (own) {
    float tv[TN], mv[TN];
    ld12(Tb + bi * 12, tv); ld12(Mb + bi * 12, mv);
    #pragma unroll
    for (int j = 0; j < TN; ++j) {
      float Tf = tv[j] + gamma * dv[j];
      float Af = av[j] + gamma * adt[j];
      d1 += mv[j] * Tf;
      d2 += (cc + c2qs[j]) * Tf;
      d3 += Af * Tf;
    }
  }
  d1 = bred(d1, red); d2 = bred(d2, red); d3 = bred(d3, red);
  float* fk = sc + 256 + k * 4;
  if (tid == 0) { atomicAdd(fk + 0, d1); atomicAdd(fk + 1, d2); atomicAdd(fk + 2, d3); }
  tbar(ctr, 2 * NBT);
  if (b == 0 && tid == 0)
    out[k] = oma * ga_readf(fk + 0) + alpha * (ga_readf(fk + 1) - 2.f * ga_readf(fk + 2));
}

extern "C" void kernel_launch(void* const* d_in, const int* in_sizes, int n_in,
                              void* d_out, int out_size, void* d_ws, size_t ws_size,
                              hipStream_t stream) {
  const float* x  = (const float*)d_in[0];
  const int*   ei = (const int*)d_in[1];
  const float* C2 = (const float*)d_in[2];
  const float* F2 = (const float*)d_in[3];
  const float* q0 = (const float*)d_in[4];
  const float* a0p = (const float*)d_in[5];
  float* out = (float*)d_out;

  char* ws = (char*)d_ws;
  int* deg    = (int*)(ws + OFF_DEG);
  int* rowptr = (int*)(ws + OFF_RP);
  int* cur    = (int*)(ws + OFF_CUR);
  int* col    = (int*)(ws + OFF_COL);
  float* sc   = (float*)(ws + OFF_SC);
  float* csg  = (float*)(ws + OFF_CS);
  float* Mb   = (float*)(ws + OFF_M);
  float* Tb   = (float*)(ws + OFF_T);
  u32x4* AtM  = (u32x4*)(ws + OFF_ATM);
  uint32_t* AtT = (uint32_t*)(ws + OFF_ATT);
  u32x4* DtM  = (u32x4*)(ws + OFF_DTM);
  uint32_t* DtT = (uint32_t*)(ws + OFF_DTT);
  u32x4* Y2M  = (u32x4*)(ws + OFF_Y2M);
  uint32_t* Y2T = (uint32_t*)(ws + OFF_Y2T);

  int initN = NN + SC_FLOATS + CS_FLOATS;
  k_init<<<(initN + 255) / 256, 256, 0, stream>>>(ws);
  k_deg<<<(NE + 255) / 256, 256, 0, stream>>>(ei, deg);
  k_scan<<<1, 1024, 0, stream>>>(deg, rowptr, cur);
  k_fill<<<(NE + 255) / 256, 256, 0, stream>>>(ei, cur, col);
  kM<<<dim3(GRX, NT), RB, 0, stream>>>(x, F2, Mb);

  int tv[NFW] = {0, 1, 2};
  for (int t = 0; t < NFW; ++t) {
    void* args[] = { (void*)&rowptr, (void*)&col, (void*)&Mb, (void*)&Tb,
                     (void*)&AtM, (void*)&AtT, (void*)&DtM, (void*)&DtT,
                     (void*)&Y2M, (void*)&Y2T, (void*)&q0, (void*)&C2,
                     (void*)&a0p, (void*)&sc, (void*)&csg, (void*)&tv[t] };
    hipLaunchCooperativeKernel((const void*)kFW, dim3(NT * NBT), dim3(TPB),
                               args, 0, stream);
  }
  void* fargs[] = { (void*)&rowptr, (void*)&col, (void*)&Mb, (void*)&Tb,
                    (void*)&AtM, (void*)&AtT, (void*)&DtM, (void*)&DtT,
                    (void*)&Y2M, (void*)&Y2T, (void*)&q0, (void*)&C2,
                    (void*)&a0p, (void*)&sc, (void*)&out };
  hipLaunchCooperativeKernel((const void*)kFin, dim3(NT * NBT), dim3(TPB),
                             fargs, 0, stream);
}

// Round 8
// 439.018 us; speedup vs baseline: 1.3642x; 1.3642x over previous
//
#include <hip/hip_runtime.h>
#include <stdint.h>

typedef float    f32x4 __attribute__((ext_vector_type(4)));
typedef uint32_t u32x4 __attribute__((ext_vector_type(4)));

#define NN 5000
#define NE 80000
#define NF 128
#define NT 16
#define TN 10
#define NFW 3
#define NSK 10
#define PW (1.0f/5000.0f)
#define RB 128
#define GRX 40
#define TPB 1024
#define NSL 5            // row slots per thread (5*1024 >= 5000)

// ---------- workspace layout (bytes) ----------
#define OFF_DEG  0u
#define OFF_RP   20224u
#define OFF_CUR  40448u
#define OFF_COL  60672u      // 320000 -> 380672
#define OFF_SCG  380672u     // 32 f32: [k*2+{0,1}] = bM,bC of latest FW iter
#define OFF_M    384000u     // f32 [16][5000][12] -> 4,224,000
#define OFF_T    4224000u    // f32 -> 8,064,000
#define OFF_ATM  8064000u    // ATC bf16 u32x4 -> 9,344,000
#define OFF_ATT  9344000u    // ATC bf16 u32   -> 9,664,000
#define OFF_DTM  9664000u    // dT bf16 -> 10,944,000
#define OFF_DTT  10944000u   // -> 11,264,000
#define OFF_Y2M  11264000u   // Y2 = dT@C2 bf16 -> 12,544,000
#define OFF_Y2T  12544000u   // -> 12,864,000
#define OFF_ADM  12864000u   // A(dT C2) gather result bf16 -> 14,144,000
#define OFF_ADT  14144000u   // -> 14,464,000

// ---------- LDS layout (bytes) ----------
#define L_YM   0        // u32x4[5000] = 80000  (Y2 stage / E cols 0-7)
#define L_YT   80000    // u32[5000]  = 20000  (Y2 tail / E cols 8-9)
#define L_RED  100000   // f32[256]
#define L_WLS  101024   // f32[16]
#define L_UNI  101088   // qvs[16] c2qs[16] qC2s[16]
#define SMEM_BYTES 101280

// ---------- helpers ----------
__device__ __forceinline__ uint32_t bfb(float x) {
  uint32_t u = __float_as_uint(x);
  return (u + 0x7fffu + ((u >> 16) & 1u)) >> 16;
}
__device__ __forceinline__ uint32_t pk(float a, float b) { return bfb(a) | (bfb(b) << 16); }
__device__ __forceinline__ float ubl(uint32_t u) { return __uint_as_float(u << 16); }
__device__ __forceinline__ float ubh(uint32_t u) { return __uint_as_float(u & 0xffff0000u); }
__device__ __forceinline__ float sigm(float z) { return 1.f / (1.f + __expf(-z)); }

__device__ __forceinline__ void ld12(const float* p, float* v) {
  f32x4 a = *(const f32x4*)p, b = *(const f32x4*)(p + 4), c = *(const f32x4*)(p + 8);
  v[0]=a[0]; v[1]=a[1]; v[2]=a[2]; v[3]=a[3]; v[4]=b[0]; v[5]=b[1]; v[6]=b[2]; v[7]=b[3];
  v[8]=c[0]; v[9]=c[1];
}
__device__ __forceinline__ void st12(float* p, const float* v) {
  *(f32x4*)p       = (f32x4){v[0], v[1], v[2], v[3]};
  *(f32x4*)(p + 4) = (f32x4){v[4], v[5], v[6], v[7]};
  *(f32x4*)(p + 8) = (f32x4){v[8], v[9], 0.f, 0.f};
}
__device__ __forceinline__ void ldbf(const u32x4* __restrict__ M4, const uint32_t* __restrict__ M1,
                                     size_t i, float* v) {
  u32x4 A = M4[i]; uint32_t B = M1[i];
  v[0]=ubl(A[0]); v[1]=ubh(A[0]); v[2]=ubl(A[1]); v[3]=ubh(A[1]);
  v[4]=ubl(A[2]); v[5]=ubh(A[2]); v[6]=ubl(A[3]); v[7]=ubh(A[3]);
  v[8]=ubl(B);    v[9]=ubh(B);
}
__device__ __forceinline__ void stbf(u32x4* __restrict__ M4, uint32_t* __restrict__ M1,
                                     size_t i, const float* v) {
  M4[i] = (u32x4){pk(v[0], v[1]), pk(v[2], v[3]), pk(v[4], v[5]), pk(v[6], v[7])};
  M1[i] = pk(v[8], v[9]);
}
// block reduce, 16 waves; includes leading sync so red can be reused
__device__ __forceinline__ float bred16(float v, float* red) {
  #pragma unroll
  for (int o = 32; o; o >>= 1) v += __shfl_xor(v, o, 64);
  __syncthreads();
  if ((threadIdx.x & 63) == 0) red[threadIdx.x >> 6] = v;
  __syncthreads();
  float r = 0.f;
  #pragma unroll
  for (int w = 0; w < 16; ++w) r += red[w];
  return r;
}

// ---------- setup kernels ----------
__global__ void k_init(int* __restrict__ deg) {
  int i = blockIdx.x * 256 + threadIdx.x;
  if (i < NN) deg[i] = 0;
}
__global__ void k_deg(const int* __restrict__ ei, int* __restrict__ deg) {
  int e = blockIdx.x * 256 + threadIdx.x;
  if (e < NE) atomicAdd(&deg[ei[e]], 1);
}
__global__ void k_scan(const int* __restrict__ deg, int* __restrict__ rowptr, int* __restrict__ cur) {
  __shared__ int scr[1024];
  int tid = threadIdx.x;
  int loc[5], s = 0;
  #pragma unroll
  for (int r = 0; r < 5; ++r) {
    int idx = tid * 5 + r;
    int d = (idx < NN) ? deg[idx] : 0;
    loc[r] = s; s += d;
  }
  scr[tid] = s; __syncthreads();
  for (int off = 1; off < 1024; off <<= 1) {
    int v = scr[tid];
    int u = (tid >= off) ? scr[tid - off] : 0;
    __syncthreads();
    scr[tid] = v + u;
    __syncthreads();
  }
  int base = (tid > 0) ? scr[tid - 1] : 0;
  #pragma unroll
  for (int r = 0; r < 5; ++r) {
    int idx = tid * 5 + r;
    if (idx < NN) { int v = base + loc[r]; rowptr[idx] = v; cur[idx] = v; }
  }
  if (tid == 1023) rowptr[NN] = scr[1023];
}
__global__ void k_fill(const int* __restrict__ ei, int* __restrict__ cur, int* __restrict__ col) {
  int e = blockIdx.x * 256 + threadIdx.x;
  if (e < NE) {
    int s = ei[e];
    int pos = atomicAdd(&cur[s], 1);
    col[pos] = ei[NE + e];
  }
}
// ---------- M build (full chip) ----------
__global__ void kM(const float* __restrict__ x, const float* __restrict__ F2,
                   float* __restrict__ Mb) {
  __shared__ float ffs[TN];
  const int k = blockIdx.y, tid = threadIdx.x;
  const int i = blockIdx.x * RB + tid;
  const float* Fk = F2 + (size_t)k * TN * NF;
  if (tid < TN) {
    float s = 0.f;
    for (int d = 0; d < NF; ++d) { float f = Fk[tid * NF + d]; s += f * f; }
    ffs[tid] = s;
  }
  __syncthreads();
  if (i >= NN) return;
  const f32x4* xr = (const f32x4*)(x + (size_t)i * NF);
  float acc[TN];
  #pragma unroll
  for (int j = 0; j < TN; ++j) acc[j] = 0.f;
  float xsq = 0.f;
  for (int dc = 0; dc < NF / 4; ++dc) {
    f32x4 xv = xr[dc];
    xsq += xv[0]*xv[0] + xv[1]*xv[1] + xv[2]*xv[2] + xv[3]*xv[3];
    #pragma unroll
    for (int j = 0; j < TN; ++j) {
      const float* Fj = Fk + j * NF + dc * 4;  // uniform -> scalar loads
      acc[j] += xv[0]*Fj[0] + xv[1]*Fj[1] + xv[2]*Fj[2] + xv[3]*Fj[3];
    }
  }
  float v[TN];
  #pragma unroll
  for (int j = 0; j < TN; ++j) v[j] = xsq + ffs[j] - 2.f * acc[j];
  st12(Mb + ((size_t)k * NN + i) * 12, v);
}

// uniforms into LDS (qvs, c2qs, qC2s); one syncthreads
__device__ __forceinline__ void uni_setup(const float* __restrict__ q0,
                                          const float* __restrict__ C2k, int k,
                                          float* qvs, float* c2qs, float* qC2s) {
  const int tid = threadIdx.x;
  if (tid < TN) {
    float mx = -1e30f, e[TN], s = 0.f;
    #pragma unroll
    for (int j = 0; j < TN; ++j) mx = fmaxf(mx, q0[k * TN + j]);
    #pragma unroll
    for (int j = 0; j < TN; ++j) { e[j] = __expf(q0[k * TN + j] - mx); s += e[j]; }
    float inv = 1.f / s;
    qvs[tid] = e[tid] * inv;
    float c2 = 0.f, qc = 0.f;
    #pragma unroll
    for (int l = 0; l < TN; ++l) {
      float c = C2k[tid * TN + l];
      c2 += c * c * e[l] * inv;              // ((C2*C2) q)[tid]
      qc += e[l] * inv * C2k[l * TN + tid];  // (q^T C2)[tid]
    }
    c2qs[tid] = c2; qC2s[tid] = qc;
  }
  __syncthreads();
}

// ---------- kFW: one full FW iteration, ONE block per template, zero atomics ----------
__global__ __launch_bounds__(TPB) void kFW(
    const int* __restrict__ rowptr, const int* __restrict__ col,
    const float* __restrict__ Mb, float* __restrict__ Tb,
    u32x4* __restrict__ AtM, uint32_t* __restrict__ AtT,
    u32x4* __restrict__ DtM, uint32_t* __restrict__ DtT,
    u32x4* __restrict__ Y2M, uint32_t* __restrict__ Y2T,
    u32x4* __restrict__ AdM, uint32_t* __restrict__ AdT_,
    const float* __restrict__ q0, const float* __restrict__ C2g,
    const float* __restrict__ a0p, float* __restrict__ scg, int t) {
  extern __shared__ char smem[];
  u32x4* LYM = (u32x4*)(smem + L_YM);
  uint32_t* LYT = (uint32_t*)(smem + L_YT);
  float* red = (float*)(smem + L_RED);
  float* wls = (float*)(smem + L_WLS);
  float* qvs = (float*)(smem + L_UNI);
  float* c2qs = qvs + 16; float* qC2s = qvs + 32;

  const int k = blockIdx.x, tid = threadIdx.x;
  const float* C2k = C2g + k * 100;
  uni_setup(q0, C2k, k, qvs, c2qs, qC2s);
  const float alpha = sigm(a0p[0]), oma = 1.f - alpha;
  const size_t kb = (size_t)k * NN;

  float gamma = 0.f;
  // ---- head: gamma + T/ATC update ----
  if (t > 0) {
    for (int i = tid; i < NN; i += TPB) { LYM[i] = Y2M[kb + i]; LYT[i] = Y2T[kb + i]; }
    __syncthreads();
    float bA = 0.f, aA = 0.f;
    for (int s = 0; s < NSL; ++s) {
      int r = s * TPB + tid;
      if (r < NN) {
        int e0 = rowptr[r], e1 = rowptr[r + 1];
        float adt[TN];
        #pragma unroll
        for (int j = 0; j < TN; ++j) adt[j] = 0.f;
        for (int e = e0; e < e1; ++e) {
          int c = col[e];
          u32x4 A = LYM[c]; uint32_t B = LYT[c];
          adt[0] += ubl(A[0]); adt[1] += ubh(A[0]); adt[2] += ubl(A[1]); adt[3] += ubh(A[1]);
          adt[4] += ubl(A[2]); adt[5] += ubh(A[2]); adt[6] += ubl(A[3]); adt[7] += ubh(A[3]);
          adt[8] += ubl(B);    adt[9] += ubh(B);
        }
        float av[TN], dv[TN];
        ldbf(AtM, AtT, kb + r, av); ldbf(DtM, DtT, kb + r, dv);
        #pragma unroll
        for (int j = 0; j < TN; ++j) { bA += av[j] * dv[j]; aA += adt[j] * dv[j]; }
        stbf(AdM, AdT_, kb + r, adt);
      }
    }
    bA = bred16(bA, red); aA = bred16(aA, red);
    const float bM = scg[k * 2 + 0], bC = scg[k * 2 + 1];
    float a_ = -2.f * alpha * aA;
    float b_ = oma * bM + alpha * (bC - 4.f * bA);
    gamma = (a_ > 0.f) ? fminf(fmaxf(-b_ / (2.f * a_ + 1e-16f), 0.f), 1.f)
                       : ((a_ + b_ < 0.f) ? 1.f : 0.f);
    for (int s = 0; s < NSL; ++s) {
      int r = s * TPB + tid;
      if (r < NN) {
        float tv[TN], dv[TN], av[TN], adt[TN];
        ld12(Tb + (kb + r) * 12, tv);
        ldbf(DtM, DtT, kb + r, dv);
        ldbf(AtM, AtT, kb + r, av);
        ldbf(AdM, AdT_, kb + r, adt);
        #pragma unroll
        for (int j = 0; j < TN; ++j) { tv[j] += gamma * dv[j]; av[j] += gamma * adt[j]; }
        st12(Tb + (kb + r) * 12, tv);
        stbf(AtM, AtT, kb + r, av);
      }
    }
  } else {
    for (int s = 0; s < NSL; ++s) {
      int r = s * TPB + tid;
      if (r < NN) {
        float dg = (float)(rowptr[r + 1] - rowptr[r]) * PW;
        float tv[TN], av[TN];
        #pragma unroll
        for (int j = 0; j < TN; ++j) { tv[j] = PW * qvs[j]; av[j] = dg * qC2s[j]; }
        st12(Tb + (kb + r) * 12, tv);
        stbf(AtM, AtT, kb + r, av);
      }
    }
  }

  // ---- G pass 1: sabs only (G never stored) ----
  float sabs = 0.f;
  for (int s = 0; s < NSL; ++s) {
    int r = s * TPB + tid;
    if (r < NN) {
      float mv[TN], av[TN];
      ld12(Mb + (kb + r) * 12, mv); ldbf(AtM, AtT, kb + r, av);
      float cc = (float)(rowptr[r + 1] - rowptr[r]) * PW;
      #pragma unroll
      for (int j = 0; j < TN; ++j)
        sabs += fabsf(oma * mv[j] + 2.f * alpha * (cc + c2qs[j] - 2.f * av[j]));
    }
  }
  sabs = bred16(sabs, red);
  const float invreg = 1.f / (0.05f * sabs * (1.f / (float)(NN * TN)) + 1e-9f);

  // ---- G pass 2: recompute G, E = exp -> LDS bf16 (overwrites staged Y2) ----
  for (int s = 0; s < NSL; ++s) {
    int r = s * TPB + tid;
    if (r < NN) {
      float mv[TN], av[TN], G[TN];
      ld12(Mb + (kb + r) * 12, mv); ldbf(AtM, AtT, kb + r, av);
      float cc = (float)(rowptr[r + 1] - rowptr[r]) * PW;
      #pragma unroll
      for (int j = 0; j < TN; ++j)
        G[j] = oma * mv[j] + 2.f * alpha * (cc + c2qs[j] - 2.f * av[j]);
      float mn = G[0];
      #pragma unroll
      for (int j = 1; j < TN; ++j) mn = fminf(mn, G[j]);
      #pragma unroll
      for (int j = 0; j < TN; ++j) G[j] = __expf(-(G[j] - mn) * invreg);
      stbf(LYM, LYT, (size_t)r, G);
    }
  }
  __syncthreads();

  // ---- Sinkhorn: 10 iterations, block-local ----
  float wl[TN], wp[TN];
  #pragma unroll
  for (int j = 0; j < TN; ++j) { wl[j] = 1.f; wp[j] = 1.f; }
  for (int it = 0; it < NSK; ++it) {
    float csl[TN];
    #pragma unroll
    for (int j = 0; j < TN; ++j) csl[j] = 0.f;
    for (int s = 0; s < NSL; ++s) {
      int r = s * TPB + tid;
      if (r < NN) {
        float E[TN];
        ldbf(LYM, LYT, (size_t)r, E);
        float dot = 0.f;
        #pragma unroll
        for (int j = 0; j < TN; ++j) dot += E[j] * wl[j];
        float u = PW * __builtin_amdgcn_rcpf(fmaxf(dot, 1e-35f));
        #pragma unroll
        for (int j = 0; j < TN; ++j) csl[j] += E[j] * u;
      }
    }
    #pragma unroll
    for (int j = 0; j < TN; ++j) {
      float vv = csl[j];
      #pragma unroll
      for (int o = 32; o; o >>= 1) vv += __shfl_xor(vv, o, 64);
      if ((tid & 63) == j) red[(tid >> 6) * 16 + j] = vv;
    }
    __syncthreads();
    if (tid < TN) {
      float ssum = 0.f;
      #pragma unroll
      for (int w = 0; w < 16; ++w) ssum += red[w * 16 + tid];
      wls[tid] = qvs[tid] * __builtin_amdgcn_rcpf(fmaxf(ssum, 1e-35f));
    }
    __syncthreads();
    #pragma unroll
    for (int j = 0; j < TN; ++j) { wp[j] = wl[j]; wl[j] = wls[j]; }
  }

  // ---- tail: dT, bM/bC, Y2 = dT@C2 ----
  float bM = 0.f, bC = 0.f;
  for (int s = 0; s < NSL; ++s) {
    int r = s * TPB + tid;
    if (r < NN) {
      float E[TN];
      ldbf(LYM, LYT, (size_t)r, E);
      float dot = 0.f;
      #pragma unroll
      for (int j = 0; j < TN; ++j) dot += E[j] * wp[j];
      float u = PW * __builtin_amdgcn_rcpf(fmaxf(dot, 1e-35f));
      float tv[TN], mv[TN], dT[TN];
      ld12(Tb + (kb + r) * 12, tv);
      ld12(Mb + (kb + r) * 12, mv);
      float cc = (float)(rowptr[r + 1] - rowptr[r]) * PW;
      #pragma unroll
      for (int j = 0; j < TN; ++j) {
        float tn = u * E[j] * wl[j];
        dT[j] = tn - tv[j];
        bM += mv[j] * dT[j];
        bC += (cc + c2qs[j]) * dT[j];
      }
      stbf(DtM, DtT, kb + r, dT);
      float y[TN];
      #pragma unroll
      for (int j = 0; j < TN; ++j) {
        float ss = 0.f;
        #pragma unroll
        for (int l = 0; l < TN; ++l) ss += dT[l] * C2k[l * TN + j];
        y[j] = ss;
      }
      stbf(Y2M, Y2T, kb + r, y);
    }
  }
  bM = bred16(bM, red); bC = bred16(bC, red);
  if (tid == 0) { scg[k * 2 + 0] = bM; scg[k * 2 + 1] = bC; }
}

// ---------- kFin: last gamma + final distance (one block per template) ----------
__global__ __launch_bounds__(TPB) void kFin(
    const int* __restrict__ rowptr, const int* __restrict__ col,
    const float* __restrict__ Mb, const float* __restrict__ Tb,
    const u32x4* __restrict__ AtM, const uint32_t* __restrict__ AtT,
    const u32x4* __restrict__ DtM, const uint32_t* __restrict__ DtT,
    const u32x4* __restrict__ Y2M, const uint32_t* __restrict__ Y2T,
    u32x4* __restrict__ AdM, uint32_t* __restrict__ AdT_,
    const float* __restrict__ q0, const float* __restrict__ C2g,
    const float* __restrict__ a0p, const float* __restrict__ scg,
    float* __restrict__ out) {
  extern __shared__ char smem[];
  u32x4* LYM = (u32x4*)(smem + L_YM);
  uint32_t* LYT = (uint32_t*)(smem + L_YT);
  float* red = (float*)(smem + L_RED);
  float* qvs = (float*)(smem + L_UNI);
  float* c2qs = qvs + 16; float* qC2s = qvs + 32;

  const int k = blockIdx.x, tid = threadIdx.x;
  const float* C2k = C2g + k * 100;
  uni_setup(q0, C2k, k, qvs, c2qs, qC2s);
  const float alpha = sigm(a0p[0]), oma = 1.f - alpha;
  const size_t kb = (size_t)k * NN;

  for (int i = tid; i < NN; i += TPB) { LYM[i] = Y2M[kb + i]; LYT[i] = Y2T[kb + i]; }
  __syncthreads();
  float bA = 0.f, aA = 0.f;
  for (int s = 0; s < NSL; ++s) {
    int r = s * TPB + tid;
    if (r < NN) {
      int e0 = rowptr[r], e1 = rowptr[r + 1];
      float adt[TN];
      #pragma unroll
      for (int j = 0; j < TN; ++j) adt[j] = 0.f;
      for (int e = e0; e < e1; ++e) {
        int c = col[e];
        u32x4 A = LYM[c]; uint32_t B = LYT[c];
        adt[0] += ubl(A[0]); adt[1] += ubh(A[0]); adt[2] += ubl(A[1]); adt[3] += ubh(A[1]);
        adt[4] += ubl(A[2]); adt[5] += ubh(A[2]); adt[6] += ubl(A[3]); adt[7] += ubh(A[3]);
        adt[8] += ubl(B);    adt[9] += ubh(B);
      }
      float av[TN], dv[TN];
      ldbf(AtM, AtT, kb + r, av); ldbf(DtM, DtT, kb + r, dv);
      #pragma unroll
      for (int j = 0; j < TN; ++j) { bA += av[j] * dv[j]; aA += adt[j] * dv[j]; }
      stbf(AdM, AdT_, kb + r, adt);
    }
  }
  bA = bred16(bA, red); aA = bred16(aA, red);
  const float bM = scg[k * 2 + 0], bC = scg[k * 2 + 1];
  float a_ = -2.f * alpha * aA;
  float b_ = oma * bM + alpha * (bC - 4.f * bA);
  float gamma = (a_ > 0.f) ? fminf(fmaxf(-b_ / (2.f * a_ + 1e-16f), 0.f), 1.f)
                           : ((a_ + b_ < 0.f) ? 1.f : 0.f);
  float d1 = 0.f, d2 = 0.f, d3 = 0.f;
  for (int s = 0; s < NSL; ++s) {
    int r = s * TPB + tid;
    if (r < NN) {
      float tv[TN], dv[TN], av[TN], adt[TN], mv[TN];
      ld12(Tb + (kb + r) * 12, tv);
      ldbf(DtM, DtT, kb + r, dv);
      ldbf(AtM, AtT, kb + r, av);
      ldbf(AdM, AdT_, kb + r, adt);
      ld12(Mb + (kb + r) * 12, mv);
      float cc = (float)(rowptr[r + 1] - rowptr[r]) * PW;
      #pragma unroll
      for (int j = 0; j < TN; ++j) {
        float Tf = tv[j] + gamma * dv[j];
        float Af = av[j] + gamma * adt[j];
        d1 += mv[j] * Tf;
        d2 += (cc + c2qs[j]) * Tf;
        d3 += Af * Tf;
      }
    }
  }
  d1 = bred16(d1, red); d2 = bred16(d2, red); d3 = bred16(d3, red);
  if (tid == 0) out[k] = oma * d1 + alpha * (d2 - 2.f * d3);
}

extern "C" void kernel_launch(void* const* d_in, const int* in_sizes, int n_in,
                              void* d_out, int out_size, void* d_ws, size_t ws_size,
                              hipStream_t stream) {
  const float* x  = (const float*)d_in[0];
  const int*   ei = (const int*)d_in[1];
  const float* C2 = (const float*)d_in[2];
  const float* F2 = (const float*)d_in[3];
  const float* q0 = (const float*)d_in[4];
  const float* a0p = (const float*)d_in[5];
  float* out = (float*)d_out;

  char* ws = (char*)d_ws;
  int* deg    = (int*)(ws + OFF_DEG);
  int* rowptr = (int*)(ws + OFF_RP);
  int* cur    = (int*)(ws + OFF_CUR);
  int* col    = (int*)(ws + OFF_COL);
  float* scg  = (float*)(ws + OFF_SCG);
  float* Mb   = (float*)(ws + OFF_M);
  float* Tb   = (float*)(ws + OFF_T);
  u32x4* AtM  = (u32x4*)(ws + OFF_ATM);
  uint32_t* AtT = (uint32_t*)(ws + OFF_ATT);
  u32x4* DtM  = (u32x4*)(ws + OFF_DTM);
  uint32_t* DtT = (uint32_t*)(ws + OFF_DTT);
  u32x4* Y2M  = (u32x4*)(ws + OFF_Y2M);
  uint32_t* Y2T = (uint32_t*)(ws + OFF_Y2T);
  u32x4* AdM  = (u32x4*)(ws + OFF_ADM);
  uint32_t* AdT_ = (uint32_t*)(ws + OFF_ADT);

  hipFuncSetAttribute((const void*)kFW, hipFuncAttributeMaxDynamicSharedMemorySize, SMEM_BYTES);
  hipFuncSetAttribute((const void*)kFin, hipFuncAttributeMaxDynamicSharedMemorySize, SMEM_BYTES);

  k_init<<<(NN + 255) / 256, 256, 0, stream>>>(deg);
  k_deg<<<(NE + 255) / 256, 256, 0, stream>>>(ei, deg);
  k_scan<<<1, 1024, 0, stream>>>(deg, rowptr, cur);
  k_fill<<<(NE + 255) / 256, 256, 0, stream>>>(ei, cur, col);
  kM<<<dim3(GRX, NT), RB, 0, stream>>>(x, F2, Mb);

  for (int t = 0; t < NFW; ++t)
    kFW<<<NT, TPB, SMEM_BYTES, stream>>>(rowptr, col, Mb, Tb, AtM, AtT, DtM, DtT,
                                         Y2M, Y2T, AdM, AdT_, q0, C2, a0p, scg, t);
  kFin<<<NT, TPB, SMEM_BYTES, stream>>>(rowptr, col, Mb, Tb, AtM, AtT, DtM, DtT,
                                        Y2M, Y2T, AdM, AdT_, q0, C2, a0p, scg, out);
}

// Round 9
// 370.828 us; speedup vs baseline: 1.6151x; 1.1839x over previous
//
#include <hip/hip_runtime.h>
#include <hip/hip_fp16.h>
#include <stdint.h>

typedef float    f32x4 __attribute__((ext_vector_type(4)));
typedef uint32_t u32x4 __attribute__((ext_vector_type(4)));

#define NN 5000
#define NE 80000
#define NF 128
#define NT 16
#define TN 10
#define NFW 3
#define NSK 10
#define PW (1.0f/5000.0f)
#define RB 128
#define GRX 40           // 40*128 = 5120 >= 5000
#define DTPB 512         // kD threads
#define DSL 10           // kD row slots (10*512 >= 5000)
#define NBD 16           // kD blocks per template
#define RPD 313          // rows per kD block (313*16 >= 5000)

// ---------- workspace layout (bytes) ----------
#define OFF_DEG  0u
#define OFF_RP   20224u
#define OFF_CUR  40448u
#define OFF_COL  60672u      // +320000 = 380672
#define OFF_SC   380672u     // 384 f32: [t*16+k]=sabs(t<3); [64+tt*64+k*4+d]=dots bM,bC,bA,aA (tt<3);
                             // [256+k*4+d]=fin; int at float-idx 320+k = ctr
#define SC_FLOATS 384
#define OFF_MM   382272u     // M f16 hi u32x4 [16*5000] -> 1,662,272
#define OFF_MT   1662272u    // M f16 tail u32 -> 1,982,272
#define OFF_T    1982272u    // T f32 [16][5000][12] -> 5,822,272
#define OFF_ATM  5822272u    // ATC bf16 -> 7,102,272
#define OFF_ATT  7102272u    // -> 7,422,272
#define OFF_DTM  7422272u    // dT bf16 -> 8,702,272
#define OFF_DTT  8702272u    // -> 9,022,272
#define OFF_Y2M  9022272u    // Y2 bf16 -> 10,302,272
#define OFF_Y2T  10302272u   // -> 10,622,272
#define OFF_ADM  10622272u   // adt bf16 -> 11,902,272
#define OFF_ADT  11902272u   // -> 12,222,272
#define OFF_GM   12222272u   // G f16 -> 13,502,272
#define OFF_GT   13502272u   // -> 13,822,272

// ---------- LDS layout for kD (bytes) ----------
#define L_EM   0        // u32x4[5000] = 80000
#define L_ET   80000    // u32[5000]   = 20000
#define L_RED  100000   // f32[128]
#define L_WLS  100512   // f32[16]
#define L_UNI  100576   // qvs[16] c2qs[16] qC2s[16]
#define SMEM_D 100768

// ---------- bf16 helpers ----------
__device__ __forceinline__ uint32_t bfb(float x) {
  uint32_t u = __float_as_uint(x);
  return (u + 0x7fffu + ((u >> 16) & 1u)) >> 16;
}
__device__ __forceinline__ uint32_t pk(float a, float b) { return bfb(a) | (bfb(b) << 16); }
__device__ __forceinline__ float ubl(uint32_t u) { return __uint_as_float(u << 16); }
__device__ __forceinline__ float ubh(uint32_t u) { return __uint_as_float(u & 0xffff0000u); }
// ---------- f16 helpers ----------
__device__ __forceinline__ uint32_t pkh(float a, float b) {
  return (uint32_t)__half_as_ushort(__float2half(a)) |
         ((uint32_t)__half_as_ushort(__float2half(b)) << 16);
}
__device__ __forceinline__ float ulh(uint32_t u) {
  return __half2float(__ushort_as_half((unsigned short)(u & 0xffffu)));
}
__device__ __forceinline__ float uhh(uint32_t u) {
  return __half2float(__ushort_as_half((unsigned short)(u >> 16)));
}
__device__ __forceinline__ float sigm(float z) { return 1.f / (1.f + __expf(-z)); }

__device__ __forceinline__ void ld12(const float* p, float* v) {
  f32x4 a = *(const f32x4*)p, b = *(const f32x4*)(p + 4), c = *(const f32x4*)(p + 8);
  v[0]=a[0]; v[1]=a[1]; v[2]=a[2]; v[3]=a[3]; v[4]=b[0]; v[5]=b[1]; v[6]=b[2]; v[7]=b[3];
  v[8]=c[0]; v[9]=c[1];
}
__device__ __forceinline__ void st12(float* p, const float* v) {
  *(f32x4*)p       = (f32x4){v[0], v[1], v[2], v[3]};
  *(f32x4*)(p + 4) = (f32x4){v[4], v[5], v[6], v[7]};
  *(f32x4*)(p + 8) = (f32x4){v[8], v[9], 0.f, 0.f};
}
__device__ __forceinline__ void ldbf(const u32x4* __restrict__ M4, const uint32_t* __restrict__ M1,
                                     size_t i, float* v) {
  u32x4 A = M4[i]; uint32_t B = M1[i];
  v[0]=ubl(A[0]); v[1]=ubh(A[0]); v[2]=ubl(A[1]); v[3]=ubh(A[1]);
  v[4]=ubl(A[2]); v[5]=ubh(A[2]); v[6]=ubl(A[3]); v[7]=ubh(A[3]);
  v[8]=ubl(B);    v[9]=ubh(B);
}
__device__ __forceinline__ void stbf(u32x4* __restrict__ M4, uint32_t* __restrict__ M1,
                                     size_t i, const float* v) {
  M4[i] = (u32x4){pk(v[0], v[1]), pk(v[2], v[3]), pk(v[4], v[5]), pk(v[6], v[7])};
  M1[i] = pk(v[8], v[9]);
}
__device__ __forceinline__ void ldhf(const u32x4* __restrict__ M4, const uint32_t* __restrict__ M1,
                                     size_t i, float* v) {
  u32x4 A = M4[i]; uint32_t B = M1[i];
  v[0]=ulh(A[0]); v[1]=uhh(A[0]); v[2]=ulh(A[1]); v[3]=uhh(A[1]);
  v[4]=ulh(A[2]); v[5]=uhh(A[2]); v[6]=ulh(A[3]); v[7]=uhh(A[3]);
  v[8]=ulh(B);    v[9]=uhh(B);
}
__device__ __forceinline__ void sthf(u32x4* __restrict__ M4, uint32_t* __restrict__ M1,
                                     size_t i, const float* v) {
  M4[i] = (u32x4){pkh(v[0], v[1]), pkh(v[2], v[3]), pkh(v[4], v[5]), pkh(v[6], v[7])};
  M1[i] = pkh(v[8], v[9]);
}
template<int W>
__device__ __forceinline__ float bredw(float v, float* red) {
  #pragma unroll
  for (int o = 32; o; o >>= 1) v += __shfl_xor(v, o, 64);
  __syncthreads();
  if ((threadIdx.x & 63) == 0) red[threadIdx.x >> 6] = v;
  __syncthreads();
  float r = 0.f;
  #pragma unroll
  for (int w = 0; w < W; ++w) r += red[w];
  return r;
}
// uniforms: qvs = softmax(q0), c2qs = (C2*C2)q, qC2s = q^T C2
__device__ __forceinline__ void uni_setup(const float* __restrict__ q0,
                                          const float* __restrict__ C2k, int k,
                                          float* qvs, float* c2qs, float* qC2s) {
  const int tid = threadIdx.x;
  if (tid < TN) {
    float mx = -1e30f, e[TN], s = 0.f;
    #pragma unroll
    for (int j = 0; j < TN; ++j) mx = fmaxf(mx, q0[k * TN + j]);
    #pragma unroll
    for (int j = 0; j < TN; ++j) { e[j] = __expf(q0[k * TN + j] - mx); s += e[j]; }
    float inv = 1.f / s;
    qvs[tid] = e[tid] * inv;
    float c2 = 0.f, qc = 0.f;
    #pragma unroll
    for (int l = 0; l < TN; ++l) {
      float c = C2k[tid * TN + l];
      c2 += c * c * e[l] * inv;
      qc += e[l] * inv * C2k[l * TN + tid];
    }
    c2qs[tid] = c2; qC2s[tid] = qc;
  }
  __syncthreads();
}
__device__ __forceinline__ float gamma_from(const float* dk, float alpha, float oma) {
  float a_ = -2.f * alpha * dk[3];
  float b_ = oma * dk[0] + alpha * (dk[1] - 4.f * dk[2]);
  return (a_ > 0.f) ? fminf(fmaxf(-b_ / (2.f * a_ + 1e-16f), 0.f), 1.f)
                    : ((a_ + b_ < 0.f) ? 1.f : 0.f);
}

// ---------- setup ----------
__global__ void k_init(char* __restrict__ ws) {
  int g = blockIdx.x * 256 + threadIdx.x;
  if (g < NN) ((int*)(ws + OFF_DEG))[g] = 0;
  int z = g - NN;
  if (z >= 0 && z < SC_FLOATS) ((float*)(ws + OFF_SC))[z] = 0.f;
}
__global__ void k_deg(const int* __restrict__ ei, int* __restrict__ deg) {
  int e = blockIdx.x * 256 + threadIdx.x;
  if (e < NE) atomicAdd(&deg[ei[e]], 1);
}
__global__ void k_scan(const int* __restrict__ deg, int* __restrict__ rowptr, int* __restrict__ cur) {
  __shared__ int scr[1024];
  int tid = threadIdx.x;
  int loc[5], s = 0;
  #pragma unroll
  for (int r = 0; r < 5; ++r) {
    int idx = tid * 5 + r;
    int d = (idx < NN) ? deg[idx] : 0;
    loc[r] = s; s += d;
  }
  scr[tid] = s; __syncthreads();
  for (int off = 1; off < 1024; off <<= 1) {
    int v = scr[tid];
    int u = (tid >= off) ? scr[tid - off] : 0;
    __syncthreads();
    scr[tid] = v + u;
    __syncthreads();
  }
  int base = (tid > 0) ? scr[tid - 1] : 0;
  #pragma unroll
  for (int r = 0; r < 5; ++r) {
    int idx = tid * 5 + r;
    if (idx < NN) { int v = base + loc[r]; rowptr[idx] = v; cur[idx] = v; }
  }
  if (tid == 1023) rowptr[NN] = scr[1023];
}
__global__ void k_fill(const int* __restrict__ ei, int* __restrict__ cur, int* __restrict__ col) {
  int e = blockIdx.x * 256 + threadIdx.x;
  if (e < NE) {
    int s = ei[e];
    int pos = atomicAdd(&cur[s], 1);
    col[pos] = ei[NE + e];
  }
}
// ---------- M build (f16 out) ----------
__global__ void kM(const float* __restrict__ x, const float* __restrict__ F2,
                   u32x4* __restrict__ MM, uint32_t* __restrict__ MT) {
  __shared__ float ffs[TN];
  const int k = blockIdx.y, tid = threadIdx.x;
  const int i = blockIdx.x * RB + tid;
  const float* Fk = F2 + (size_t)k * TN * NF;
  if (tid < TN) {
    float s = 0.f;
    for (int d = 0; d < NF; ++d) { float f = Fk[tid * NF + d]; s += f * f; }
    ffs[tid] = s;
  }
  __syncthreads();
  if (i >= NN) return;
  const f32x4* xr = (const f32x4*)(x + (size_t)i * NF);
  float acc[TN];
  #pragma unroll
  for (int j = 0; j < TN; ++j) acc[j] = 0.f;
  float xsq = 0.f;
  for (int dc = 0; dc < NF / 4; ++dc) {
    f32x4 xv = xr[dc];
    xsq += xv[0]*xv[0] + xv[1]*xv[1] + xv[2]*xv[2] + xv[3]*xv[3];
    #pragma unroll
    for (int j = 0; j < TN; ++j) {
      const float* Fj = Fk + j * NF + dc * 4;
      acc[j] += xv[0]*Fj[0] + xv[1]*Fj[1] + xv[2]*Fj[2] + xv[3]*Fj[3];
    }
  }
  float v[TN];
  #pragma unroll
  for (int j = 0; j < TN; ++j) v[j] = xsq + ffs[j] - 2.f * acc[j];
  sthf(MM, MT, (size_t)k * NN + i, v);
}

// ---------- kB: gamma + T/ATC update + G(f16) + sabs (elementwise, full chip) ----------
__global__ __launch_bounds__(RB) void kB(
    const int* __restrict__ rowptr,
    const u32x4* __restrict__ MM, const uint32_t* __restrict__ MT,
    float* __restrict__ Tb, u32x4* __restrict__ AtM, uint32_t* __restrict__ AtT,
    const u32x4* __restrict__ DtM, const uint32_t* __restrict__ DtT,
    const u32x4* __restrict__ AdM, const uint32_t* __restrict__ AdT_,
    u32x4* __restrict__ GM, uint32_t* __restrict__ GT,
    const float* __restrict__ q0, const float* __restrict__ C2g,
    const float* __restrict__ a0p, float* __restrict__ sc, int t) {
  __shared__ float qvs[16], c2qs[16], qC2s[16];
  __shared__ float redl[2];
  const int k = blockIdx.y, tid = threadIdx.x;
  const int i = blockIdx.x * RB + tid;
  uni_setup(q0, C2g + k * 100, k, qvs, c2qs, qC2s);
  const float alpha = sigm(a0p[0]), oma = 1.f - alpha;
  float sabs = 0.f;
  if (i < NN) {
    const size_t bi = (size_t)k * NN + i;
    const int dg = rowptr[i + 1] - rowptr[i];
    const float cc = (float)dg * PW;
    float Trow[TN], Arow[TN];
    if (t == 0) {
      #pragma unroll
      for (int j = 0; j < TN; ++j) { Trow[j] = PW * qvs[j]; Arow[j] = (float)dg * PW * qC2s[j]; }
    } else {
      const float* dk = sc + 64 + (size_t)(t - 1) * 64 + k * 4;
      const float gamma = gamma_from(dk, alpha, oma);
      float tv[TN], dv[TN], av[TN], adv[TN];
      ld12(Tb + bi * 12, tv);
      ldbf(DtM, DtT, bi, dv);
      ldbf(AtM, AtT, bi, av);
      ldbf(AdM, AdT_, bi, adv);
      #pragma unroll
      for (int j = 0; j < TN; ++j) { Trow[j] = tv[j] + gamma * dv[j]; Arow[j] = av[j] + gamma * adv[j]; }
    }
    st12(Tb + bi * 12, Trow);
    stbf(AtM, AtT, bi, Arow);
    float mv[TN], G[TN];
    ldhf(MM, MT, bi, mv);
    #pragma unroll
    for (int j = 0; j < TN; ++j) {
      G[j] = oma * mv[j] + 2.f * alpha * (cc + c2qs[j] - 2.f * Arow[j]);
      sabs += fabsf(G[j]);
    }
    sthf(GM, GT, bi, G);
  }
  sabs = bredw<2>(sabs, redl);
  if (tid == 0) atomicAdd(sc + t * NT + k, sabs);
}

// ---------- kD: full-G-in-LDS, redundant block-local Sinkhorn, tail dT/Y2/bM/bC ----------
__global__ __launch_bounds__(DTPB) void kD(
    const int* __restrict__ rowptr, const float* __restrict__ Tb,
    const u32x4* __restrict__ MM, const uint32_t* __restrict__ MT,
    const u32x4* __restrict__ GM, const uint32_t* __restrict__ GT,
    u32x4* __restrict__ DtM, uint32_t* __restrict__ DtT,
    u32x4* __restrict__ Y2M, uint32_t* __restrict__ Y2T,
    const float* __restrict__ q0, const float* __restrict__ C2g,
    const float* __restrict__ a0p, float* __restrict__ sc, int t) {
  extern __shared__ char smem[];
  u32x4* EM = (u32x4*)(smem + L_EM);
  uint32_t* ET = (uint32_t*)(smem + L_ET);
  float* red = (float*)(smem + L_RED);
  float* wls = (float*)(smem + L_WLS);
  float* qvs = (float*)(smem + L_UNI);
  float* c2qs = qvs + 16; float* qC2s = qvs + 32;

  const int b = blockIdx.x, k = blockIdx.y, tid = threadIdx.x;
  const float* C2k = C2g + k * 100;
  uni_setup(q0, C2k, k, qvs, c2qs, qC2s);
  const size_t kb = (size_t)k * NN;

  // copy full G (f16) into LDS
  for (int i = tid; i < NN; i += DTPB) { EM[i] = GM[kb + i]; ET[i] = GT[kb + i]; }
  __syncthreads();
  const float invreg = 1.f / (0.05f * sc[t * NT + k] * (1.f / (float)(NN * TN)) + 1e-9f);

  // E = exp(-(G - rowmin)/reg) in place (row shift absorbed exactly by u)
  #pragma unroll
  for (int s = 0; s < DSL; ++s) {
    int r = s * DTPB + tid;
    if (r < NN) {
      float g[TN];
      ldhf(EM, ET, (size_t)r, g);
      float mn = g[0];
      #pragma unroll
      for (int j = 1; j < TN; ++j) mn = fminf(mn, g[j]);
      #pragma unroll
      for (int j = 0; j < TN; ++j) g[j] = __expf(-(g[j] - mn) * invreg);
      sthf(EM, ET, (size_t)r, g);
    }
  }
  __syncthreads();

  // Sinkhorn: 10 iterations, block-local (redundant across the 16 blocks, identical results)
  float wl[TN], wp[TN];
  #pragma unroll
  for (int j = 0; j < TN; ++j) { wl[j] = 1.f; wp[j] = 1.f; }
  for (int it = 0; it < NSK; ++it) {
    float csl[TN];
    #pragma unroll
    for (int j = 0; j < TN; ++j) csl[j] = 0.f;
    #pragma unroll
    for (int s = 0; s < DSL; ++s) {
      int r = s * DTPB + tid;
      if (r < NN) {
        float E[TN];
        ldhf(EM, ET, (size_t)r, E);
        float dot = 0.f;
        #pragma unroll
        for (int j = 0; j < TN; ++j) dot += E[j] * wl[j];
        float u = PW * __builtin_amdgcn_rcpf(fmaxf(dot, 1e-35f));
        #pragma unroll
        for (int j = 0; j < TN; ++j) csl[j] += E[j] * u;
      }
    }
    #pragma unroll
    for (int j = 0; j < TN; ++j) {
      float vv = csl[j];
      #pragma unroll
      for (int o = 32; o; o >>= 1) vv += __shfl_xor(vv, o, 64);
      if ((tid & 63) == j) red[(tid >> 6) * 16 + j] = vv;
    }
    __syncthreads();
    if (tid < TN) {
      float ssum = 0.f;
      #pragma unroll
      for (int w = 0; w < DTPB / 64; ++w) ssum += red[w * 16 + tid];
      wls[tid] = qvs[tid] * __builtin_amdgcn_rcpf(fmaxf(ssum, 1e-35f));
    }
    __syncthreads();
    #pragma unroll
    for (int j = 0; j < TN; ++j) { wp[j] = wl[j]; wl[j] = wls[j]; }
  }

  // tail: own rows only
  float bM = 0.f, bC = 0.f;
  if (tid < RPD) {
    int r = b * RPD + tid;
    if (r < NN) {
      float E[TN];
      ldhf(EM, ET, (size_t)r, E);
      float dot = 0.f;
      #pragma unroll
      for (int j = 0; j < TN; ++j) dot += E[j] * wp[j];
      float u = PW * __builtin_amdgcn_rcpf(fmaxf(dot, 1e-35f));
      float tv[TN], mv[TN], dT[TN];
      ld12(Tb + (kb + r) * 12, tv);
      ldhf(MM, MT, kb + r, mv);
      float cc = (float)(rowptr[r + 1] - rowptr[r]) * PW;
      #pragma unroll
      for (int j = 0; j < TN; ++j) {
        float tn = u * E[j] * wl[j];
        dT[j] = tn - tv[j];
        bM += mv[j] * dT[j];
        bC += (cc + c2qs[j]) * dT[j];
      }
      stbf(DtM, DtT, kb + r, dT);
      float y[TN];
      #pragma unroll
      for (int j = 0; j < TN; ++j) {
        float ss = 0.f;
        #pragma unroll
        for (int l = 0; l < TN; ++l) ss += dT[l] * C2k[l * TN + j];
        y[j] = ss;
      }
      stbf(Y2M, Y2T, kb + r, y);
    }
  }
  bM = bredw<DTPB / 64>(bM, red);
  bC = bredw<DTPB / 64>(bC, red);
  if (tid == 0) {
    float* dk = sc + 64 + (size_t)t * 64 + k * 4;
    atomicAdd(dk + 0, bM);
    atomicAdd(dk + 1, bC);
  }
}

// ---------- kA: gather Y2 -> adt; bA/aA dots; store adt ----------
__global__ __launch_bounds__(RB) void kA(
    const int* __restrict__ rowptr, const int* __restrict__ col,
    const u32x4* __restrict__ Y2M, const uint32_t* __restrict__ Y2T,
    const u32x4* __restrict__ AtM, const uint32_t* __restrict__ AtT,
    const u32x4* __restrict__ DtM, const uint32_t* __restrict__ DtT,
    u32x4* __restrict__ AdM, uint32_t* __restrict__ AdT_,
    float* __restrict__ sc, int tt) {
  __shared__ float redl[2];
  const int k = blockIdx.y, tid = threadIdx.x;
  const int i = blockIdx.x * RB + tid;
  float bA = 0.f, aA = 0.f;
  if (i < NN) {
    const size_t bi = (size_t)k * NN + i;
    const u32x4* YM = Y2M + (size_t)k * NN;
    const uint32_t* YT = Y2T + (size_t)k * NN;
    int e0 = rowptr[i], e1 = rowptr[i + 1];
    float adt[TN];
    #pragma unroll
    for (int j = 0; j < TN; ++j) adt[j] = 0.f;
    for (int e = e0; e < e1; ++e) {
      int c = col[e];
      u32x4 A = YM[c]; uint32_t B = YT[c];
      adt[0] += ubl(A[0]); adt[1] += ubh(A[0]); adt[2] += ubl(A[1]); adt[3] += ubh(A[1]);
      adt[4] += ubl(A[2]); adt[5] += ubh(A[2]); adt[6] += ubl(A[3]); adt[7] += ubh(A[3]);
      adt[8] += ubl(B);    adt[9] += ubh(B);
    }
    float av[TN], dv[TN];
    ldbf(AtM, AtT, bi, av);
    ldbf(DtM, DtT, bi, dv);
    #pragma unroll
    for (int j = 0; j < TN; ++j) { bA += av[j] * dv[j]; aA += adt[j] * dv[j]; }
    stbf(AdM, AdT_, bi, adt);
  }
  bA = bredw<2>(bA, redl);
  aA = bredw<2>(aA, redl);
  if (tid == 0) {
    float* dk = sc + 64 + (size_t)tt * 64 + k * 4;
    atomicAdd(dk + 2, bA);
    atomicAdd(dk + 3, aA);
  }
}

// ---------- kFin: final gamma + distance (elementwise) ----------
__global__ __launch_bounds__(RB) void kFin(
    const int* __restrict__ rowptr,
    const u32x4* __restrict__ MM, const uint32_t* __restrict__ MT,
    const float* __restrict__ Tb,
    const u32x4* __restrict__ AtM, const uint32_t* __restrict__ AtT,
    const u32x4* __restrict__ DtM, const uint32_t* __restrict__ DtT,
    const u32x4* __restrict__ AdM, const uint32_t* __restrict__ AdT_,
    const float* __restrict__ q0, const float* __restrict__ C2g,
    const float* __restrict__ a0p, float* __restrict__ sc,
    float* __restrict__ out) {
  __shared__ float qvs[16], c2qs[16], qC2s[16];
  __shared__ float redl[2];
  const int k = blockIdx.y, tid = threadIdx.x;
  const int i = blockIdx.x * RB + tid;
  uni_setup(q0, C2g + k * 100, k, qvs, c2qs, qC2s);
  const float alpha = sigm(a0p[0]), oma = 1.f - alpha;
  const float gamma = gamma_from(sc + 64 + (size_t)(NFW - 1) * 64 + k * 4, alpha, oma);
  float d1 = 0.f, d2 = 0.f, d3 = 0.f;
  if (i < NN) {
    const size_t bi = (size_t)k * NN + i;
    float tv[TN], dv[TN], av[TN], adv[TN], mv[TN];
    ld12(Tb + bi * 12, tv);
    ldbf(DtM, DtT, bi, dv);
    ldbf(AtM, AtT, bi, av);
    ldbf(AdM, AdT_, bi, adv);
    ldhf(MM, MT, bi, mv);
    float cc = (float)(rowptr[i + 1] - rowptr[i]) * PW;
    #pragma unroll
    for (int j = 0; j < TN; ++j) {
      float Tf = tv[j] + gamma * dv[j];
      float Af = av[j] + gamma * adv[j];
      d1 += mv[j] * Tf;
      d2 += (cc + c2qs[j]) * Tf;
      d3 += Af * Tf;
    }
  }
  d1 = bredw<2>(d1, redl);
  d2 = bredw<2>(d2, redl);
  d3 = bredw<2>(d3, redl);
  float* fk = sc + 256 + k * 4;
  if (tid == 0) {
    atomicAdd(fk + 0, d1);
    atomicAdd(fk + 1, d2);
    atomicAdd(fk + 2, d3);
  }
  asm volatile("s_waitcnt vmcnt(0)" ::: "memory");
  __syncthreads();
  if (tid == 0) {
    int* ctr = (int*)(sc + 320) + k;
    int old = __hip_atomic_fetch_add(ctr, 1, __ATOMIC_RELAXED, __HIP_MEMORY_SCOPE_AGENT);
    if (old == GRX - 1) {
      float f0 = __hip_atomic_fetch_add(fk + 0, 0.f, __ATOMIC_RELAXED, __HIP_MEMORY_SCOPE_AGENT);
      float f1 = __hip_atomic_fetch_add(fk + 1, 0.f, __ATOMIC_RELAXED, __HIP_MEMORY_SCOPE_AGENT);
      float f2 = __hip_atomic_fetch_add(fk + 2, 0.f, __ATOMIC_RELAXED, __HIP_MEMORY_SCOPE_AGENT);
      out[k] = oma * f0 + alpha * (f1 - 2.f * f2);
    }
  }
}

extern "C" void kernel_launch(void* const* d_in, const int* in_sizes, int n_in,
                              void* d_out, int out_size, void* d_ws, size_t ws_size,
                              hipStream_t stream) {
  const float* x  = (const float*)d_in[0];
  const int*   ei = (const int*)d_in[1];
  const float* C2 = (const float*)d_in[2];
  const float* F2 = (const float*)d_in[3];
  const float* q0 = (const float*)d_in[4];
  const float* a0p = (const float*)d_in[5];
  float* out = (float*)d_out;

  char* ws = (char*)d_ws;
  int* deg    = (int*)(ws + OFF_DEG);
  int* rowptr = (int*)(ws + OFF_RP);
  int* cur    = (int*)(ws + OFF_CUR);
  int* col    = (int*)(ws + OFF_COL);
  float* sc   = (float*)(ws + OFF_SC);
  u32x4* MM   = (u32x4*)(ws + OFF_MM);
  uint32_t* MT = (uint32_t*)(ws + OFF_MT);
  float* Tb   = (float*)(ws + OFF_T);
  u32x4* AtM  = (u32x4*)(ws + OFF_ATM);
  uint32_t* AtT = (uint32_t*)(ws + OFF_ATT);
  u32x4* DtM  = (u32x4*)(ws + OFF_DTM);
  uint32_t* DtT = (uint32_t*)(ws + OFF_DTT);
  u32x4* Y2M  = (u32x4*)(ws + OFF_Y2M);
  uint32_t* Y2T = (uint32_t*)(ws + OFF_Y2T);
  u32x4* AdM  = (u32x4*)(ws + OFF_ADM);
  uint32_t* AdT_ = (uint32_t*)(ws + OFF_ADT);
  u32x4* GM   = (u32x4*)(ws + OFF_GM);
  uint32_t* GT = (uint32_t*)(ws + OFF_GT);

  hipFuncSetAttribute((const void*)kD, hipFuncAttributeMaxDynamicSharedMemorySize, SMEM_D);

  const dim3 rg(GRX, NT), rb(RB);
  const dim3 dg_(NBD, NT), db(DTPB);

  k_init<<<(NN + SC_FLOATS + 255) / 256, 256, 0, stream>>>(ws);
  k_deg<<<(NE + 255) / 256, 256, 0, stream>>>(ei, deg);
  k_scan<<<1, 1024, 0, stream>>>(deg, rowptr, cur);
  k_fill<<<(NE + 255) / 256, 256, 0, stream>>>(ei, cur, col);
  kM<<<rg, rb, 0, stream>>>(x, F2, MM, MT);

  for (int t = 0; t < NFW; ++t) {
    if (t > 0)
      kA<<<rg, rb, 0, stream>>>(rowptr, col, Y2M, Y2T, AtM, AtT, DtM, DtT,
                                AdM, AdT_, sc, t - 1);
    kB<<<rg, rb, 0, stream>>>(rowptr, MM, MT, Tb, AtM, AtT, DtM, DtT, AdM, AdT_,
                              GM, GT, q0, C2, a0p, sc, t);
    kD<<<dg_, db, SMEM_D, stream>>>(rowptr, Tb, MM, MT, GM, GT, DtM, DtT,
                                    Y2M, Y2T, q0, C2, a0p, sc, t);
  }
  kA<<<rg, rb, 0, stream>>>(rowptr, col, Y2M, Y2T, AtM, AtT, DtM, DtT,
                            AdM, AdT_, sc, NFW - 1);
  kFin<<<rg, rb, 0, stream>>>(rowptr, MM, MT, Tb, AtM, AtT, DtM, DtT, AdM, AdT_,
                              q0, C2, a0p, sc, out);
}